// Round 1
// baseline (190.863 us; speedup 1.0000x reference)
//
#include <hip/hip_runtime.h>

// Problem constants (match reference)
#define NVIEW 11
#define RAD 5
#define GH 64
#define GW 64
#define WINSZ (NVIEW * NVIEW)   // 121
#define NCH 6
#define NOUT (NCH * WINSZ)      // 726

// One block per env, 128 threads.
// Phase 1: stage 11x11 window (with WALL padding + consumed-center override) in LDS.
// Phase 2: write 726 channel outputs coalesced.
__global__ __launch_bounds__(128) void env_step_obs_kernel(
    const float* __restrict__ grids,          // (N, 64, 64)
    const float* __restrict__ agent_energy,   // (N,)
    const float* __restrict__ lut,            // (5,)
    const int*   __restrict__ agent_x,        // (N,)
    const int*   __restrict__ agent_y,        // (N,)
    const int*   __restrict__ actions,        // (N,)
    const int*   __restrict__ action_deltas,  // (9, 2) = (dy, dx)
    float*       __restrict__ out)            // (N, 6, 11, 11)
{
    const int n   = blockIdx.x;
    const int tid = threadIdx.x;

    __shared__ float s_win[WINSZ];
    __shared__ float s_lut[5];
    __shared__ float s_energy;

    // ---- per-env scalar step logic (redundant per thread; loads broadcast in L1) ----
    const int a  = actions[n];
    const int dy = action_deltas[2 * a];
    const int dx = action_deltas[2 * a + 1];
    const int y0 = agent_y[n];
    const int x0 = agent_x[n];

    int ny = min(max(y0 + dy, 0), GH - 1);
    int nx = min(max(x0 + dx, 0), GW - 1);

    const float* g = grids + (size_t)n * (GH * GW);

    // blocked move: target is WALL -> stay in place
    const float tgt = g[ny * GW + nx];
    if (tgt == 1.0f) { ny = y0; nx = x0; }

    const float cell      = g[ny * GW + nx];
    const bool  is_food   = (cell == 2.0f);
    const bool  is_poison = (cell == 3.0f);
    const bool  consumed  = is_food || is_poison;
    const float reward    = (is_food ? 10.0f : 0.0f) - (is_poison ? 10.0f : 0.0f);

    if (tid < 5)  s_lut[tid] = lut[tid];
    if (tid == 0) s_energy   = agent_energy[n] - 1.0f + reward;

    // ---- phase 1: gather window into LDS ----
    if (tid < WINSZ) {
        const int i  = tid / NVIEW;          // const divisor -> cheap
        const int j  = tid - i * NVIEW;
        const int yy = ny - RAD + i;
        const int xx = nx - RAD + j;
        float v;
        if (yy < 0 || yy >= GH || xx < 0 || xx >= GW) {
            v = 1.0f;                        // WALL padding
        } else {
            v = g[yy * GW + xx];
        }
        // consumed food/poison at the agent's landing cell becomes EMPTY;
        // that cell is exactly the window center (RAD, RAD).
        if (consumed && tid == (RAD * NVIEW + RAD)) v = 0.0f;
        s_win[tid] = v;
    }
    __syncthreads();

    // ---- phase 2: write 6 channels, coalesced ----
    const float energy = s_energy;
    float* o_base = out + (size_t)n * NOUT;
    #pragma unroll
    for (int o = tid; o < NOUT; o += 128) {
        const int   c = o / WINSZ;           // const divisor 121 -> magic mul
        const int   p = o - c * WINSZ;
        const float v = s_win[p];
        float r;
        switch (c) {
            case 0:  r = (v == 2.0f) ? 1.0f : 0.0f; break;   // food mask
            case 1:  r = (v == 3.0f) ? 1.0f : 0.0f; break;   // poison mask
            case 2:  r = (v == 1.0f) ? 1.0f : 0.0f; break;   // wall mask
            case 3:  r = s_lut[(int)v];             break;   // interestingness
            case 4:  r = v;                         break;   // raw window
            default: r = energy;                    break;   // energy broadcast
        }
        o_base[o] = r;
    }
}

extern "C" void kernel_launch(void* const* d_in, const int* in_sizes, int n_in,
                              void* d_out, int out_size, void* d_ws, size_t ws_size,
                              hipStream_t stream) {
    const float* grids   = (const float*)d_in[0];
    const float* energy  = (const float*)d_in[1];
    const float* lut     = (const float*)d_in[2];
    const int*   agent_x = (const int*)d_in[3];
    const int*   agent_y = (const int*)d_in[4];
    // d_in[5] = agent_steps (unused by reference output)
    const int*   actions = (const int*)d_in[6];
    const int*   deltas  = (const int*)d_in[7];
    float*       out     = (float*)d_out;

    const int n_envs = in_sizes[1];  // agent_energy count = N_ENVS

    env_step_obs_kernel<<<n_envs, 128, 0, stream>>>(
        grids, energy, lut, agent_x, agent_y, actions, deltas, out);
}

// Round 2
// 188.124 us; speedup vs baseline: 1.0146x; 1.0146x over previous
//
#include <hip/hip_runtime.h>

// Problem constants (match reference)
#define NVIEW 11
#define RAD 5
#define GH 64
#define GW 64
#define WINSZ (NVIEW * NVIEW)   // 121
#define NCH 6
#define NOUT (NCH * WINSZ)      // 726

// One 64-lane WAVE per env. 256-thread blocks = 4 independent waves.
// No LDS, no __syncthreads: lane i holds window cells i and i+64 in registers,
// and every output channel is an elementwise transform of the window value
// (or the energy broadcast), so each lane writes outputs for its own cells.
__global__ __launch_bounds__(256) void env_step_obs_kernel(
    const float* __restrict__ grids,          // (N, 64, 64)
    const float* __restrict__ agent_energy,   // (N,)
    const float* __restrict__ lut,            // (5,)
    const int*   __restrict__ agent_x,        // (N,)
    const int*   __restrict__ agent_y,        // (N,)
    const int*   __restrict__ actions,        // (N,)
    const int*   __restrict__ action_deltas,  // (9, 2) = (dy, dx)
    float*       __restrict__ out,            // (N, 6, 11, 11)
    int n_envs)
{
    const int lane = threadIdx.x & 63;
    const int wave = threadIdx.x >> 6;
    const int n    = blockIdx.x * 4 + wave;   // env id (wave-uniform)
    if (n >= n_envs) return;

    // ---- per-env step logic (redundant per lane; same-address loads broadcast) ----
    const int a  = actions[n];
    const int dy = action_deltas[2 * a];
    const int dx = action_deltas[2 * a + 1];
    const int y0 = agent_y[n];
    const int x0 = agent_x[n];

    int ny = min(max(y0 + dy, 0), GH - 1);
    int nx = min(max(x0 + dx, 0), GW - 1);

    const float* g = grids + (size_t)n * (GH * GW);

    const float tgt = g[ny * GW + nx];
    if (tgt == 1.0f) { ny = y0; nx = x0; }          // blocked by wall: stay

    const float cell      = g[ny * GW + nx];
    const bool  is_food   = (cell == 2.0f);
    const bool  is_poison = (cell == 3.0f);
    const bool  consumed  = is_food || is_poison;
    const float reward    = (is_food ? 10.0f : 0.0f) - (is_poison ? 10.0f : 0.0f);
    const float energy    = agent_energy[n] - 1.0f + reward;

    // grid values are exact small integers {0,1,2,3}; lut[4] is unreachable
    const float l0 = lut[0], l1 = lut[1], l2 = lut[2], l3 = lut[3];

    // ---- gather: lane holds window cells p = lane and p = lane + 64 ----
    float v[2];
    #pragma unroll
    for (int r = 0; r < 2; ++r) {
        const int p = lane + r * 64;
        float val = 1.0f;                           // WALL pad default
        if (p < WINSZ) {
            const int i  = p / NVIEW;               // const divisor
            const int j  = p - i * NVIEW;
            const int yy = ny - RAD + i;
            const int xx = nx - RAD + j;
            if (yy >= 0 && yy < GH && xx >= 0 && xx < GW) val = g[yy * GW + xx];
            // consumed food/poison at landing cell == window center (5,5)
            if (consumed && p == (RAD * NVIEW + RAD)) val = 0.0f;
        }
        v[r] = val;
    }

    // ---- write 6 channels; each lane writes its own cells' transforms ----
    float* ob = out + (size_t)n * NOUT;
    #pragma unroll
    for (int r = 0; r < 2; ++r) {
        const int p = lane + r * 64;
        if (p < WINSZ) {
            const float val = v[r];
            ob[0 * WINSZ + p] = (val == 2.0f) ? 1.0f : 0.0f;   // food mask
            ob[1 * WINSZ + p] = (val == 3.0f) ? 1.0f : 0.0f;   // poison mask
            ob[2 * WINSZ + p] = (val == 1.0f) ? 1.0f : 0.0f;   // wall mask
            const float lv = (val == 0.0f) ? l0
                           : (val == 1.0f) ? l1
                           : (val == 2.0f) ? l2 : l3;
            ob[3 * WINSZ + p] = lv;                            // interestingness
            ob[4 * WINSZ + p] = val;                           // raw window
            ob[5 * WINSZ + p] = energy;                        // energy broadcast
        }
    }
}

extern "C" void kernel_launch(void* const* d_in, const int* in_sizes, int n_in,
                              void* d_out, int out_size, void* d_ws, size_t ws_size,
                              hipStream_t stream) {
    const float* grids   = (const float*)d_in[0];
    const float* energy  = (const float*)d_in[1];
    const float* lut     = (const float*)d_in[2];
    const int*   agent_x = (const int*)d_in[3];
    const int*   agent_y = (const int*)d_in[4];
    // d_in[5] = agent_steps (unused by reference output)
    const int*   actions = (const int*)d_in[6];
    const int*   deltas  = (const int*)d_in[7];
    float*       out     = (float*)d_out;

    const int n_envs = in_sizes[1];                 // agent_energy count = N_ENVS
    const int blocks = (n_envs + 3) / 4;            // 4 waves (envs) per block

    env_step_obs_kernel<<<blocks, 256, 0, stream>>>(
        grids, energy, lut, agent_x, agent_y, actions, deltas, out, n_envs);
}